// Round 18
// baseline (77.801 us; speedup 1.0000x reference)
//
#include <hip/hip_runtime.h>
#include <cmath>

// x,y: (16,3,512,512) f32. Fused separable-Gaussian SSIM, scalar mean output.
// 2-row rounds with 20KB LDS (8 blocks/CU by LDS; ~20 waves/CU at VGPR~100):
//   rolling 12-row register ring (x,y) shared across 4 rounds, 2-row prefetch
//   under each h-pass; v-conv 2 cols/thread; h-conv 2 rows x 128 lanes x 4
//   cols (all threads active). Bank-swizzled LDS, XCD block swizzle, rcp div.
constexpr int IMG_H = 512;
constexpr int IMG_W = 512;
constexpr int PLANES = 48;
constexpr int R_OUT = 8;                 // output rows per block (4 rounds of 2)
constexpr int BANDS = IMG_H / R_OUT;     // 64
constexpr int PSTR = 512;                // field-row dwords; col c at dword c
constexpr int NSLOT = 64;                // global accumulator slots (64B apart)
constexpr int NBLK = PLANES * BANDS;     // 3072 (divisible by 8 XCDs)
constexpr long long TOTAL_PIX = (long long)PLANES * IMG_H * IMG_W;

struct GWin { float g[11]; };

// XOR bank swizzle on within-field-row dword offset (bits 2..4 ^= bits 5..7).
__device__ __forceinline__ int swzd(int d) { return d ^ (((d >> 5) & 7) << 2); }
__device__ __forceinline__ int swzd4(int b) { return b ^ ((b >> 3) & 7); }

template<bool CHK>
__device__ __forceinline__ float2 ld2(const float* __restrict__ base, int gr, int c0) {
    if (CHK && (unsigned)gr >= (unsigned)IMG_H) return make_float2(0.f, 0.f);
    return *(const float2*)(base + (size_t)gr * IMG_W + c0);
}

// horizontal 11-tap conv + SSIM over one LDS row (5 fields), 4 cols per lane.
// w20[i] = col 4l-8+i (blocks l-2..l+2, clamped); lanes 0,1,126,127 mask
// out-of-image taps in registers.
__device__ __forceinline__ float hpass4(const float* __restrict__ fr0,
                                        int l, const int (&pb)[5],
                                        const GWin& win) {
    float m[5][4];
#pragma unroll
    for (int f = 0; f < 5; ++f) {
        const float* fr = fr0 + f * PSTR;
        float w20[20];
#pragma unroll
        for (int B = 0; B < 5; ++B) {
            const float4 v = *(const float4*)&fr[pb[B]];
            w20[4 * B + 0] = v.x;  w20[4 * B + 1] = v.y;
            w20[4 * B + 2] = v.z;  w20[4 * B + 3] = v.w;
        }
        if (l == 0)   { w20[3] = w20[4] = w20[5] = w20[6] = w20[7] = 0.f; }
        if (l == 1)   { w20[3] = 0.f; }
        if (l == 126) { w20[16] = 0.f; }
        if (l == 127) { w20[12] = w20[13] = w20[14] = w20[15] = w20[16] = 0.f; }
        // output col c = 4l+j: window cols c-5..c+5 -> w20[j+3+k], k=0..10
#pragma unroll
        for (int j = 0; j < 4; ++j) {
            float s = 0.f;
#pragma unroll
            for (int k = 0; k < 11; ++k) s += win.g[k] * w20[j + 3 + k];
            m[f][j] = s;
        }
    }
    float ls = 0.f;
#pragma unroll
    for (int u = 0; u < 4; ++u) {
        const float mx  = m[0][u], my  = m[1][u];
        const float mxx = m[2][u], myy = m[3][u], mxy = m[4][u];
        const float mu_x_sq = mx * mx;
        const float mu_y_sq = my * my;
        const float mu_xy   = mx * my;
        const float sig_x  = mxx - mu_x_sq;
        const float sig_y  = myy - mu_y_sq;
        const float sig_xy = mxy - mu_xy;
        const float C1 = 0.01f * 0.01f;
        const float C2 = 0.03f * 0.03f;
        const float n = (2.f * mu_xy + C1) * (2.f * sig_xy + C2);
        const float d = (mu_x_sq + mu_y_sq + C1) * (sig_x + sig_y + C2);
        ls += n * __builtin_amdgcn_rcpf(d + 1e-8f);   // ~1 ulp; mean-safe
    }
    return ls;
}

template<bool CHK>
__device__ __forceinline__ float band_body(const float* __restrict__ xp,
                                           const float* __restrict__ yp,
                                           int r0, int c0, int tid,
                                           float* __restrict__ hb,   // [2][5][PSTR]
                                           const GWin& win)
{
    const int pws = swzd(2 * tid);       // v-write physical dword (b64-contiguous)
    const int row = tid >> 7, l = tid & 127;
    int pb[5];
#pragma unroll
    for (int B = 0; B < 5; ++B) {        // hoisted h-read addresses (clamped)
        int blk = l - 2 + B;
        blk = blk < 0 ? 0 : (blk > 127 ? 127 : blk);
        pb[B] = 4 * swzd4(blk);
    }

    // 12-slot rolling ring: slot k holds image row (rbase - 5 + k)
    float2 xr[12], yr[12];
#pragma unroll
    for (int i = 0; i < 12; ++i) {
        xr[i] = ld2<CHK>(xp, r0 - 5 + i, c0);
        yr[i] = ld2<CHK>(yp, r0 - 5 + i, c0);
    }

    float lsum = 0.f;

#pragma unroll 1
    for (int rr = 0; rr < 4; ++rr) {
        const int rbase = r0 + 2 * rr;

        // ---- vertical 11-tap conv of {x,y,xx,yy,xy} for rows rbase, rbase+1 ----
        float2 acc[2][5];
#pragma unroll
        for (int j = 0; j < 2; ++j)
#pragma unroll
            for (int f = 0; f < 5; ++f) acc[j][f] = make_float2(0.f, 0.f);

#pragma unroll
        for (int k = 0; k < 12; ++k) {
            const float2 xv = xr[k], yv = yr[k];
            const float2 pxx = make_float2(xv.x * xv.x, xv.y * xv.y);
            const float2 pyy = make_float2(yv.x * yv.x, yv.y * yv.y);
            const float2 pxy = make_float2(xv.x * yv.x, xv.y * yv.y);
            if (k < 11) {                        // row rbase, tap k
                const float g = win.g[k];
                acc[0][0].x += g * xv.x;   acc[0][0].y += g * xv.y;
                acc[0][1].x += g * yv.x;   acc[0][1].y += g * yv.y;
                acc[0][2].x += g * pxx.x;  acc[0][2].y += g * pxx.y;
                acc[0][3].x += g * pyy.x;  acc[0][3].y += g * pyy.y;
                acc[0][4].x += g * pxy.x;  acc[0][4].y += g * pxy.y;
            }
            if (k > 0) {                         // row rbase+1, tap k-1
                const float g = win.g[k - 1];
                acc[1][0].x += g * xv.x;   acc[1][0].y += g * xv.y;
                acc[1][1].x += g * yv.x;   acc[1][1].y += g * yv.y;
                acc[1][2].x += g * pxx.x;  acc[1][2].y += g * pxx.y;
                acc[1][3].x += g * pyy.x;  acc[1][3].y += g * pyy.y;
                acc[1][4].x += g * pxy.x;  acc[1][4].y += g * pxy.y;
            }
        }

#pragma unroll
        for (int j = 0; j < 2; ++j)
#pragma unroll
            for (int f = 0; f < 5; ++f)
                *(float2*)&hb[(j * 5 + f) * PSTR + pws] = acc[j][f];

        __syncthreads();

        // prefetch next round's two new rows under the h-pass (T14 split)
        float2 px0{}, py0{}, px1{}, py1{};
        if (rr < 3) {
            px0 = ld2<CHK>(xp, rbase + 7, c0);  py0 = ld2<CHK>(yp, rbase + 7, c0);
            px1 = ld2<CHK>(xp, rbase + 8, c0);  py1 = ld2<CHK>(yp, rbase + 8, c0);
        }

        lsum += hpass4(hb + row * 5 * PSTR, l, pb, win);

        __syncthreads();   // protect hbuf before next round's writes

        // shift ring by 2, commit prefetched rows (static indices)
#pragma unroll
        for (int k = 0; k < 10; ++k) { xr[k] = xr[k + 2]; yr[k] = yr[k + 2]; }
        xr[10] = px0;  yr[10] = py0;
        xr[11] = px1;  yr[11] = py1;
    }
    return lsum;
}

__global__ __launch_bounds__(256)
void ssim_r18_kernel(const float* __restrict__ x,
                     const float* __restrict__ y,
                     double* __restrict__ accum,
                     GWin win)
{
    __shared__ __align__(16) float hbuf[2 * 5 * PSTR];   // exactly 20480 B

    const int tid = threadIdx.x;
    // XCD-aware swizzle: consecutive logical bands share one XCD's L2.
    const int bid = blockIdx.x;
    const int L   = (bid & 7) * (NBLK / 8) + (bid >> 3);
    const int band  = L & (BANDS - 1);
    const int plane = L >> 6;
    const int r0    = band * R_OUT;
    const int c0    = tid * 2;

    const float* __restrict__ xp = x + (size_t)plane * (IMG_H * IMG_W);
    const float* __restrict__ yp = y + (size_t)plane * (IMG_H * IMG_W);

    float lsum;
    if (band >= 1 && band <= BANDS - 2)
        lsum = band_body<false>(xp, yp, r0, c0, tid, hbuf, win);
    else
        lsum = band_body<true>(xp, yp, r0, c0, tid, hbuf, win);

    // wave reduction, then one scattered global atomic per wave (no LDS)
#pragma unroll
    for (int off = 32; off; off >>= 1) lsum += __shfl_down(lsum, off);
    if ((tid & 63) == 0) {
        const int wid = L * 4 + (tid >> 6);
        atomicAdd(&accum[(wid & (NSLOT - 1)) * 8], (double)lsum);  // 64B stride
    }
}

__global__ void ssim_finalize_kernel(const double* __restrict__ accum,
                                     float* __restrict__ out)
{
    double s = 0.0;
    for (int i = 0; i < NSLOT; ++i) s += accum[i * 8];
    out[0] = (float)(s / (double)TOTAL_PIX);
}

extern "C" void kernel_launch(void* const* d_in, const int* in_sizes, int n_in,
                              void* d_out, int out_size, void* d_ws, size_t ws_size,
                              hipStream_t stream) {
    const float* x = (const float*)d_in[0];
    const float* y = (const float*)d_in[1];
    float* out = (float*)d_out;
    double* accum = (double*)d_ws;

    GWin win;
    {
        double g[11], s = 0.0;
        for (int i = 0; i < 11; ++i) {
            double d = (double)i - 5.0;
            g[i] = std::exp(-(d * d) / (2.0 * 1.5 * 1.5));
            s += g[i];
        }
        for (int i = 0; i < 11; ++i) win.g[i] = (float)(g[i] / s);
    }

    (void)hipMemsetAsync(d_ws, 0, NSLOT * 8 * sizeof(double), stream);

    ssim_r18_kernel<<<NBLK, 256, 0, stream>>>(x, y, accum, win);
    ssim_finalize_kernel<<<1, 1, 0, stream>>>(accum, out);
}